// Round 11
// baseline (676.080 us; speedup 1.0000x reference)
//
#include <hip/hip_runtime.h>

// Seq2SeqWithAlignment: enc/dec LSTM -> hpre -> logits logsumexp -> Viterbi align.
// K=64 enc steps, T=128 dec tokens (127 dec steps used), H=512, E=100, V=32000.

#define K_ENC 64
#define HID   512
#define EMB   100
#define VOC   32000
#define G4    2048   // 4*HID

typedef __attribute__((ext_vector_type(8))) short  short8;
typedef __attribute__((ext_vector_type(4))) float  f32x4;
typedef __attribute__((ext_vector_type(4))) int    i32x4;
typedef unsigned long long u64;

#define LOG2E 1.4426950408889634f
#define LN2   0.6931471805599453f

__device__ __forceinline__ unsigned short f2bf(float f) {
  union { float f; unsigned u; } x; x.f = f;
  unsigned r = x.u + 0x7FFFu + ((x.u >> 16) & 1u);  // RNE
  return (unsigned short)(r >> 16);
}

__device__ __forceinline__ float fast_sigmoid(float x) {
  return __builtin_amdgcn_rcpf(1.f + __builtin_amdgcn_exp2f(-LOG2E * x));
}
__device__ __forceinline__ float fast_tanh(float x) {
  return 1.f - 2.f * __builtin_amdgcn_rcpf(1.f + __builtin_amdgcn_exp2f(2.f * LOG2E * x));
}

// ---------------- workspace layout (float offsets) ----------------
#define OFF_PAD   0         // 256 floats: scratch (zeroed)
#define OFF_HBUF  256       // 4096 floats = 2048 u64: tagged h channels [grp][slot][512]
#define OFF_G0E   4352      // 64*2048  : enc Wih@x + bih + bhh
#define OFF_G0D   135424    // 127*2048 : dec
#define OFF_EENC  395520    // 64*512
#define OFF_D     428288    // 127*512
#define OFF_EWE   493312    // 64*100   : log2e * Eenc@We_E^T
#define OFF_DWD   499712    // 127*100  : log2e * (D@We_D^T + beh)
#define OFF_BEM   512412    // 32000    : log2e * bem
#define OFF_SUM   544412    // 127*64   : sum of 2^s over v (atomic)
#define OFF_EM    552540    // 127*64   : emission
#define OFF_WEM   560668    // ushort[4096000]: Wem bf16 in MFMA-B fragment-linear layout
// total ~10.4 MB

// ---------------- merged prep: WemPrep (16000 blks) + G0 (1528) + Zero (49) ----------------
#define PREP_WEM_BLKS 16000
#define PREP_G0_BLKS  1528
__global__ __launch_bounds__(256) void kPrep(const int* __restrict__ x, const int* __restrict__ y,
                    const float* __restrict__ emb,
                    const float* __restrict__ eWih, const float* __restrict__ ebih,
                    const float* __restrict__ ebhh,
                    const float* __restrict__ dWih, const float* __restrict__ dbih,
                    const float* __restrict__ dbhh,
                    const float* __restrict__ Wem, const float* __restrict__ bem,
                    float* __restrict__ ws) {
  const int b = blockIdx.x;
  const int tid = threadIdx.x;
  if (b < PREP_WEM_BLKS) {
    // Wem -> bf16 MFMA-B fragment-linear layout; bem scaled
    int gid = b * 256 + tid;                 // < 4096000
    int vt = gid >> 11;
    int kb = (gid >> 9) & 3;
    int L  = (gid >> 3) & 63;
    int j  = gid & 7;
    int v = vt * 16 + (L & 15);
    int k = kb * 32 + ((L >> 4) << 3) + j;
    float val = (k < EMB) ? Wem[v * EMB + k] : 0.f;
    ((unsigned short*)(ws + OFF_WEM))[gid] = f2bf(val);
    if (gid < VOC) ws[OFF_BEM + gid] = bem[gid] * LOG2E;
  } else if (b < PREP_WEM_BLKS + PREP_G0_BLKS) {
    // G0 = Wih @ emb[tok] + bih + bhh
    int gid = (b - PREP_WEM_BLKS) * 256 + tid;
    const int enc_total = K_ENC * G4;
    if (gid >= enc_total + 127 * G4) return;
    bool enc = gid < enc_total;
    int loc = enc ? gid : gid - enc_total;
    int t = loc >> 11, r = loc & (G4 - 1);
    int tok = enc ? x[t] : y[t];
    const float* Wr = (enc ? eWih : dWih) + r * EMB;
    const float* er = emb + tok * EMB;
    float s = 0.f;
    #pragma unroll 4
    for (int e = 0; e < EMB; ++e) s += er[e] * Wr[e];
    s += enc ? (ebih[r] + ebhh[r]) : (dbih[r] + dbhh[r]);
    ws[(enc ? OFF_G0E : OFF_G0D) + t * G4 + r] = s;
  } else {
    // zero init: scratch + tagged h channels (tag0/val0) + sumexp
    int gid = (b - PREP_WEM_BLKS - PREP_G0_BLKS) * 256 + tid;
    if (gid < 4352) ws[gid] = 0.f;
    else if (gid < 4352 + 127 * 64) ws[OFF_SUM + gid - 4352] = 0.f;
  }
}

// ---------------- persistent LSTM: 64 WGs, tagged-data protocol (R10-proven) ----------------
// Transport ledger (R0..R11): only MALL-coherent ops are promptly visible
// cross-CU. Proven fastest (R10, 1.86us/step): atomicExch tagged publish +
// throttled sc0 sc1 dwordx4 poll of the tagged data + end-of-step barrier.
// R11 lesson: removing s_sleep(1) un-throttles the poll and congests MALL for
// the producers' exchanges (236->350us) — keep the sleep and the barrier.
// R12 addition: kProj FUSED into the poll shadow. At iteration t, h_lds holds
// the full h_{t-1} (= Eenc/D row t-1). Waves 4-7 each own one projection
// output e = wg*4+(wv-4) (25 WGs x 4 = all 100 e's): 8 LDS MACs + 6-level
// shfl_xor + 1 store, overlapped with the gate-compute waves. One extra
// poll-only iteration (t == steps) projects the final row. Projection writes
// are plain stores, read only across the kernel boundary (coherence-safe).
// Poll is BOUNDED: guard expiry => finite wrong answer, never a hang.
#define STEP_GUARD 16384

__global__ __launch_bounds__(512, 2) void kLstm(const float* __restrict__ eWhh,
                                                const float* __restrict__ dWhh,
                                                const float* __restrict__ Weh,
                                                const float* __restrict__ beh,
                                                float* __restrict__ ws) {
  const int grp = blockIdx.x >> 5;            // 0=enc, 1=dec
  const int wg  = blockIdx.x & 31;
  const float* __restrict__ Whh = grp ? dWhh : eWhh;
  const float* __restrict__ G0  = ws + (grp ? OFF_G0D : OFF_G0E);
  float* hs = ws + (grp ? OFF_D : OFF_EENC);
  float* proj = ws + (grp ? OFF_DWD : OFF_EWE);
  u64* hb = (u64*)(ws + OFF_HBUF) + grp * 1024;   // [2][512] tagged words
  const int steps = grp ? 127 : K_ENC;
  const int tid = threadIdx.x;
  const int jl = tid >> 5, sub = tid & 31;
  const int j = wg * 16 + jl;                 // owned h index
  const int wv = tid >> 6, lane = tid & 63;   // wave index / lane for projection
  __shared__ float h_lds[32 * 20];            // [sub][16] padded to 20 (bank spread)

  // projection setup: waves 4-7 own e = wg*4 + (wv-4); weights in VGPRs
  const int e = wg * 4 + (wv - 4);
  const bool do_proj = (wv >= 4) && (e < EMB);
  float4 pw0 = {0.f, 0.f, 0.f, 0.f}, pw1 = {0.f, 0.f, 0.f, 0.f};
  float pbias = 0.f;
  if (do_proj) {
    const float* wr = Weh + e * 1024 + (grp ? HID : 0) + lane * 8;
    pw0 = *(const float4*)wr;
    pw1 = *(const float4*)(wr + 4);
    if (grp) pbias = beh[e];
  }

  float cst = 0.f;
  for (int t = 0; t <= steps; ++t) {
    // weight slice + G0: issued BEFORE the poll; latency hides under it
    float4 w4[16];
    float g0i = 0.f, g0f = 0.f, g0g = 0.f, g0o = 0.f;
    if (t < steps) {
      #pragma unroll
      for (int g = 0; g < 4; ++g)
        #pragma unroll
        for (int q = 0; q < 4; ++q)
          w4[g * 4 + q] = *(const float4*)&Whh[(g * HID + j) * HID + sub * 16 + q * 4];
      g0i = G0[t * G4 + j];
      g0f = G0[t * G4 + HID + j];
      g0g = G0[t * G4 + 2 * HID + j];
      g0o = G0[t * G4 + 3 * HID + j];
    }
    // ---- poll tagged data: 4 waves, 2 words/lane, one dwordx4 sweep ----
    if (tid < 256) {
      const u64* src = hb + (t & 1) * 512 + tid * 2;
      i32x4 v;
      int guard = 0;
      for (;;) {
        asm volatile("global_load_dwordx4 %0, %1, off sc0 sc1\n\t"
                     "s_waitcnt vmcnt(0)"
                     : "=v"(v) : "v"(src) : "memory");
        if ((v[1] == t && v[3] == t) || ++guard >= STEP_GUARD) break;
        __builtin_amdgcn_s_sleep(1);
      }
      int k0 = tid * 2, k1 = k0 + 1;
      union { int u; float f; } c0, c1; c0.u = v[0]; c1.u = v[2];
      h_lds[(k0 >> 4) * 20 + (k0 & 15)] = c0.f;
      h_lds[(k1 >> 4) * 20 + (k1 & 15)] = c1.f;
    }
    __syncthreads();
    // ---- fused projection of row t-1 (h_lds = h_{t-1}), waves 4-7 ----
    if (t >= 1 && do_proj) {
      float p = 0.f;
      #pragma unroll
      for (int i = 0; i < 4; ++i) {
        int k = lane * 8 + i;
        p += ((const float*)&pw0)[i] * h_lds[(k >> 4) * 20 + (k & 15)];
      }
      #pragma unroll
      for (int i = 4; i < 8; ++i) {
        int k = lane * 8 + i;
        p += ((const float*)&pw1)[i - 4] * h_lds[(k >> 4) * 20 + (k & 15)];
      }
      #pragma unroll
      for (int d = 1; d < 64; d <<= 1) p += __shfl_xor(p, d);
      if (lane == 0) proj[(t - 1) * EMB + e] = (p + pbias) * LOG2E;
    }
    if (t < steps) {
      float h[16];
      #pragma unroll
      for (int kk = 0; kk < 16; ++kk) h[kk] = h_lds[sub * 20 + kk];
      float p0 = 0.f, p1 = 0.f, p2 = 0.f, p3 = 0.f;
      #pragma unroll
      for (int q = 0; q < 4; ++q) {
        p0 += w4[0+q].x*h[q*4+0] + w4[0+q].y*h[q*4+1] + w4[0+q].z*h[q*4+2] + w4[0+q].w*h[q*4+3];
        p1 += w4[4+q].x*h[q*4+0] + w4[4+q].y*h[q*4+1] + w4[4+q].z*h[q*4+2] + w4[4+q].w*h[q*4+3];
        p2 += w4[8+q].x*h[q*4+0] + w4[8+q].y*h[q*4+1] + w4[8+q].z*h[q*4+2] + w4[8+q].w*h[q*4+3];
        p3 += w4[12+q].x*h[q*4+0] + w4[12+q].y*h[q*4+1] + w4[12+q].z*h[q*4+2] + w4[12+q].w*h[q*4+3];
      }
      #pragma unroll
      for (int d = 1; d <= 16; d <<= 1) {     // reduce over 32 sub-lanes (stays in 32-half)
        p0 += __shfl_xor(p0, d); p1 += __shfl_xor(p1, d);
        p2 += __shfl_xor(p2, d); p3 += __shfl_xor(p3, d);
      }
      float si = fast_sigmoid(g0i + p0);
      float sf = fast_sigmoid(g0f + p1);
      float gG = fast_tanh(g0g + p2);
      float so = fast_sigmoid(g0o + p3);
      cst = sf * cst + si * gG;
      float hn = so * fast_tanh(cst);
      // publish h_{t+1}: one tagged atomicExch per owned index (MALL, async)
      if (sub == 0) {
        union { float f; unsigned u; } hu; hu.f = hn;
        u64 pack = ((u64)(unsigned)(t + 1) << 32) | (u64)hu.u;
        atomicExch(&hb[((t + 1) & 1) * 512 + j], pack);
        hs[t * HID + j] = hn;
      }
    }
    __syncthreads();   // h_lds safe for next iteration's stagers
  }
}

// ---------------- fused logits GEMM (bf16 MFMA) + online sum(2^s) ----------------
__global__ __launch_bounds__(256) void kLogits(float* __restrict__ ws) {
  const int t = blockIdx.x >> 2;
  const int chunk = blockIdx.x & 3;
  const int tid = threadIdx.x;
  const int lane = tid & 63;
  const int wv = tid >> 6;
  const int quad = lane >> 4, l15 = lane & 15;
  __shared__ __align__(16) unsigned short A[64 * 128];   // hpre_s bf16, [m][k] k-padded to 128
  const float* EWe = ws + OFF_EWE;
  const float* DWd = ws + OFF_DWD + t * EMB;
  for (int idx = tid; idx < 64 * 128; idx += 256) {
    int m = idx >> 7, k = idx & 127;
    float hv = 0.f;
    if (k < EMB) { float s = EWe[m * EMB + k] + DWd[k]; hv = s > 0.f ? s : 0.f; }
    A[idx] = f2bf(hv);
  }
  __syncthreads();
  short8 af[4][4];   // A fragments persistent in VGPRs: [mtile][kblock]
  #pragma unroll
  for (int mt = 0; mt < 4; ++mt)
    #pragma unroll
    for (int kb = 0; kb < 4; ++kb)
      af[mt][kb] = *(const short8*)&A[(mt * 16 + l15) * 128 + kb * 32 + quad * 8];
  const unsigned short* wem = (const unsigned short*)(ws + OFF_WEM);
  const float* bem_s = ws + OFF_BEM;
  float rs[4][4];
  #pragma unroll
  for (int a = 0; a < 4; ++a)
    #pragma unroll
    for (int b = 0; b < 4; ++b) rs[a][b] = 0.f;
  int vt = chunk * 500 + wv;
  short8 nb0, nb1, nb2, nb3; float nbi;
  nb0 = *(const short8*)&wem[(vt * 4 + 0) * 512 + lane * 8];
  nb1 = *(const short8*)&wem[(vt * 4 + 1) * 512 + lane * 8];
  nb2 = *(const short8*)&wem[(vt * 4 + 2) * 512 + lane * 8];
  nb3 = *(const short8*)&wem[(vt * 4 + 3) * 512 + lane * 8];
  nbi = bem_s[vt * 16 + l15];
  for (int ii = wv; ii < 500; ii += 4) {
    short8 cb0 = nb0, cb1 = nb1, cb2 = nb2, cb3 = nb3;
    float cbi = nbi;
    int nvt = vt + 4;
    if (ii + 4 < 500) {   // software pipeline next B tile
      nb0 = *(const short8*)&wem[(nvt * 4 + 0) * 512 + lane * 8];
      nb1 = *(const short8*)&wem[(nvt * 4 + 1) * 512 + lane * 8];
      nb2 = *(const short8*)&wem[(nvt * 4 + 2) * 512 + lane * 8];
      nb3 = *(const short8*)&wem[(nvt * 4 + 3) * 512 + lane * 8];
      nbi = bem_s[nvt * 16 + l15];
    }
    f32x4 acc[4];
    #pragma unroll
    for (int mt = 0; mt < 4; ++mt) acc[mt] = (f32x4){cbi, cbi, cbi, cbi};  // init with bem
    #pragma unroll
    for (int mt = 0; mt < 4; ++mt) {
      acc[mt] = __builtin_amdgcn_mfma_f32_16x16x32_bf16(af[mt][0], cb0, acc[mt], 0, 0, 0);
      acc[mt] = __builtin_amdgcn_mfma_f32_16x16x32_bf16(af[mt][1], cb1, acc[mt], 0, 0, 0);
      acc[mt] = __builtin_amdgcn_mfma_f32_16x16x32_bf16(af[mt][2], cb2, acc[mt], 0, 0, 0);
      acc[mt] = __builtin_amdgcn_mfma_f32_16x16x32_bf16(af[mt][3], cb3, acc[mt], 0, 0, 0);
    }
    #pragma unroll
    for (int mt = 0; mt < 4; ++mt)
      #pragma unroll
      for (int r = 0; r < 4; ++r)
        rs[mt][r] += __builtin_amdgcn_exp2f(acc[mt][r]);   // s already includes log2e scale
    vt = nvt;
  }
  // reduce across the 16 column-lanes of each quad, then one atomic per row
  #pragma unroll
  for (int d = 1; d < 16; d <<= 1)
    #pragma unroll
    for (int mt = 0; mt < 4; ++mt)
      #pragma unroll
      for (int r = 0; r < 4; ++r)
        rs[mt][r] += __shfl_xor(rs[mt][r], d);
  if (l15 == 0) {
    float* sum = ws + OFF_SUM + t * 64;
    #pragma unroll
    for (int mt = 0; mt < 4; ++mt)
      #pragma unroll
      for (int r = 0; r < 4; ++r)
        atomicAdd(&sum[mt * 16 + quad * 4 + r], rs[mt][r]);
  }
}

// ---------------- emission = ln2 * (s_word - log2(sum 2^s)), s_word in fp32 ----------------
__global__ __launch_bounds__(256) void kEmission(const int* __restrict__ y,
                                                 const float* __restrict__ Wem,
                                                 float* __restrict__ ws) {
  int gid = blockIdx.x * 256 + threadIdx.x;
  if (gid >= 127 * 64) return;
  int t = gid >> 6, m = gid & 63;
  const float* ew = ws + OFF_EWE + m * EMB;
  const float* dw = ws + OFF_DWD + t * EMB;
  int wt = y[t + 1];
  const float* wr = Wem + wt * EMB;
  float s = ws[OFF_BEM + wt];
  #pragma unroll 4
  for (int e = 0; e < EMB; ++e) {
    float h = ew[e] + dw[e];
    h = h > 0.f ? h : 0.f;
    s += h * wr[e];
  }
  ws[OFF_EM + gid] = LN2 * (s - __builtin_amdgcn_logf(ws[OFF_SUM + gid]));
}

// ---------------- Viterbi: prefix-max trick + backtrace ----------------
__global__ __launch_bounds__(256) void kViterbi(const float* __restrict__ ws, float* __restrict__ out) {
  __shared__ float em_lds[127 * 64];
  __shared__ int   inds[128 * 64];
  __shared__ float sval;
  const int tid = threadIdx.x;
  for (int i = tid; i < 127 * 64; i += 256) em_lds[i] = ws[OFF_EM + i];
  if (tid < 64) inds[tid] = 0;   // indices row 0
  __syncthreads();
  if (tid < 64) {
    const int j = tid;
    const float fs = -0.4054651081081644f;   // log(128/192)
    const float fe = -1.0986122886681098f;   // log(64/192)
    float pa = 0.f;
    float emnext = em_lds[j];
    for (int t = 0; t < 127; ++t) {
      float emc = emnext;
      if (t < 126) emnext = em_lds[(t + 1) * 64 + j];
      float v = fmaf(-fs, (float)j, pa);   // q[j]
      int idx = j;
      #pragma unroll
      for (int d = 1; d < 64; d <<= 1) {   // inclusive prefix max, earliest argmax on ties
        float vv = __shfl_up(v, d);
        int   ii = __shfl_up(idx, d);
        bool cur = v > vv;                 // strict >: keep earlier index on ties
        v   = cur ? v : vv;
        idx = cur ? idx : ii;
      }
      pa = v + fe + fs * (float)j + emc;
      inds[(t + 1) * 64 + j] = idx;
    }
    if (j == 63) sval = pa;
  }
  __syncthreads();
  if (tid == 0) {
    int ind = 63;
    for (int t = 127; t >= 0; --t) {
      ind = inds[t * 64 + ind];
      out[t] = (float)ind;
    }
    out[128] = sval;
  }
}

extern "C" void kernel_launch(void* const* d_in, const int* in_sizes, int n_in,
                              void* d_out, int out_size, void* d_ws, size_t ws_size,
                              hipStream_t stream) {
  const int*   x    = (const int*)d_in[0];
  const int*   y    = (const int*)d_in[1];
  const float* emb  = (const float*)d_in[2];
  const float* eWih = (const float*)d_in[3];
  const float* eWhh = (const float*)d_in[4];
  const float* ebih = (const float*)d_in[5];
  const float* ebhh = (const float*)d_in[6];
  const float* dWih = (const float*)d_in[7];
  const float* dWhh = (const float*)d_in[8];
  const float* dbih = (const float*)d_in[9];
  const float* dbhh = (const float*)d_in[10];
  const float* Weh  = (const float*)d_in[11];
  const float* beh  = (const float*)d_in[12];
  const float* Wem  = (const float*)d_in[13];
  const float* bem  = (const float*)d_in[14];
  float* ws  = (float*)d_ws;
  float* out = (float*)d_out;

  hipLaunchKernelGGL(kPrep,     dim3(PREP_WEM_BLKS + PREP_G0_BLKS + 49), dim3(256), 0, stream,
                     x, y, emb, eWih, ebih, ebhh, dWih, dbih, dbhh, Wem, bem, ws);
  hipLaunchKernelGGL(kLstm,     dim3(64),    dim3(512), 0, stream, eWhh, dWhh, Weh, beh, ws);
  hipLaunchKernelGGL(kLogits,   dim3(508),   dim3(256), 0, stream, ws);
  hipLaunchKernelGGL(kEmission, dim3(32),    dim3(256), 0, stream, y, Wem, ws);
  hipLaunchKernelGGL(kViterbi,  dim3(1),     dim3(256), 0, stream, ws, out);
}

// Round 15
// 512.974 us; speedup vs baseline: 1.3180x; 1.3180x over previous
//
#include <hip/hip_runtime.h>

// Seq2SeqWithAlignment: enc/dec LSTM -> hpre -> logits logsumexp -> Viterbi align.
// K=64 enc steps, T=128 dec tokens (127 dec steps used), H=512, E=100, V=32000.

#define K_ENC 64
#define HID   512
#define EMB   100
#define VOC   32000
#define G4    2048   // 4*HID

typedef __attribute__((ext_vector_type(8))) short  short8;
typedef __attribute__((ext_vector_type(4))) float  f32x4;
typedef __attribute__((ext_vector_type(4))) int    i32x4;
typedef unsigned long long u64;

#define LOG2E 1.4426950408889634f
#define LN2   0.6931471805599453f

__device__ __forceinline__ unsigned short f2bf(float f) {
  union { float f; unsigned u; } x; x.f = f;
  unsigned r = x.u + 0x7FFFu + ((x.u >> 16) & 1u);  // RNE
  return (unsigned short)(r >> 16);
}

__device__ __forceinline__ float fast_sigmoid(float x) {
  return __builtin_amdgcn_rcpf(1.f + __builtin_amdgcn_exp2f(-LOG2E * x));
}
__device__ __forceinline__ float fast_tanh(float x) {
  return 1.f - 2.f * __builtin_amdgcn_rcpf(1.f + __builtin_amdgcn_exp2f(2.f * LOG2E * x));
}

// ---------------- workspace layout (float offsets) ----------------
#define OFF_PAD   0         // 256 floats: scratch (zeroed)
#define OFF_HBUF  256       // 4096 floats = 2048 u64: tagged h channels [grp][slot][512]
#define OFF_G0E   4352      // 64*2048  : enc Wih@x + bih + bhh
#define OFF_G0D   135424    // 127*2048 : dec
#define OFF_EENC  395520    // 64*512
#define OFF_D     428288    // 127*512
#define OFF_EWE   493312    // 64*100   : log2e * Eenc@We_E^T
#define OFF_DWD   499712    // 127*100  : log2e * (D@We_D^T + beh)
#define OFF_BEM   512412    // 32000    : log2e * bem
#define OFF_SUM   544412    // 127*64   : sum of 2^s over v (atomic)
#define OFF_EM    552540    // 127*64   : emission
#define OFF_WEM   560668    // ushort[4096000]: Wem bf16 in MFMA-B fragment-linear layout
// total ~10.4 MB

// ---------------- serial prep: G0 (1528 blks) + zero-init (49 blks) ----------------
// Only what kLstm needs at t=0. Wem-prep moved INTO the kLstm launch (idle CUs).
#define PREP_G0_BLKS 1528
__global__ __launch_bounds__(256) void kPrep0(const int* __restrict__ x, const int* __restrict__ y,
                    const float* __restrict__ emb,
                    const float* __restrict__ eWih, const float* __restrict__ ebih,
                    const float* __restrict__ ebhh,
                    const float* __restrict__ dWih, const float* __restrict__ dbih,
                    const float* __restrict__ dbhh,
                    float* __restrict__ ws) {
  const int b = blockIdx.x;
  const int tid = threadIdx.x;
  if (b < PREP_G0_BLKS) {
    // G0 = Wih @ emb[tok] + bih + bhh
    int gid = b * 256 + tid;
    const int enc_total = K_ENC * G4;
    if (gid >= enc_total + 127 * G4) return;
    bool enc = gid < enc_total;
    int loc = enc ? gid : gid - enc_total;
    int t = loc >> 11, r = loc & (G4 - 1);
    int tok = enc ? x[t] : y[t];
    const float* Wr = (enc ? eWih : dWih) + r * EMB;
    const float* er = emb + tok * EMB;
    float s = 0.f;
    #pragma unroll 4
    for (int e = 0; e < EMB; ++e) s += er[e] * Wr[e];
    s += enc ? (ebih[r] + ebhh[r]) : (dbih[r] + dbhh[r]);
    ws[(enc ? OFF_G0E : OFF_G0D) + t * G4 + r] = s;
  } else {
    // zero init: scratch + tagged h channels (tag0/val0) + sumexp
    int gid = (b - PREP_G0_BLKS) * 256 + tid;
    if (gid < 4352) ws[gid] = 0.f;
    else if (gid < 4352 + 127 * 64) ws[OFF_SUM + gid - 4352] = 0.f;
  }
}

// ---------------- persistent LSTM (64 sync WGs) + overlapped Wem-prep (8000 WGs) ----------------
// Transport ledger (R0..R12): only MALL-coherent ops are promptly visible
// cross-CU. Proven fastest (R10, 1.86us/step, twice-measured 236us): atomicExch
// tagged publish (tag<<32|f32bits) + throttled sc0 sc1 dwordx4 poll of the
// tagged data (s_sleep(1) per sweep — R11: removing it congests MALL, +48%)
// + end-of-step barrier (R11: removing it desyncs waves, more traffic).
// R12 lesson: ANY work inserted between detect and publish multiplies by 127
// (fused projection: +193us). The sync loop below is byte-exact R10.
// R13: blocks 64.. run the Wem bf16 re-layout (needed only by kLogits, which
// runs after this kernel in stream order) on the ~192 idle CUs, removing it
// from the serial prep chain. CP dispatches blocks in order -> the 64 sync WGs
// get CUs first; prep WGs add ~0.1 TB/s background HBM traffic (negligible).
// Poll is BOUNDED: guard expiry => finite wrong answer, never a hang.
#define STEP_GUARD 16384

__global__ __launch_bounds__(512, 2) void kLstm(const float* __restrict__ eWhh,
                                                const float* __restrict__ dWhh,
                                                const float* __restrict__ Wem,
                                                const float* __restrict__ bem,
                                                float* __restrict__ ws) {
  const int b = blockIdx.x;
  const int tid = threadIdx.x;
  if (b >= 64) {
    // ---- Wem -> bf16 MFMA-B fragment-linear layout; bem scaled (overlapped) ----
    int gid = (b - 64) * 512 + tid;             // < 4,096,000 = 8000*512
    int vt = gid >> 11;
    int kb = (gid >> 9) & 3;
    int L  = (gid >> 3) & 63;
    int j  = gid & 7;
    int v = vt * 16 + (L & 15);
    int k = kb * 32 + ((L >> 4) << 3) + j;
    float val = (k < EMB) ? Wem[v * EMB + k] : 0.f;
    ((unsigned short*)(ws + OFF_WEM))[gid] = f2bf(val);
    if (gid < VOC) ws[OFF_BEM + gid] = bem[gid] * LOG2E;
    return;
  }
  const int grp = b >> 5;                     // 0=enc, 1=dec
  const int wg  = b & 31;
  const float* __restrict__ Whh = grp ? dWhh : eWhh;
  const float* __restrict__ G0  = ws + (grp ? OFF_G0D : OFF_G0E);
  float* hs = ws + (grp ? OFF_D : OFF_EENC);
  u64* hb = (u64*)(ws + OFF_HBUF) + grp * 1024;   // [2][512] tagged words
  const int steps = grp ? 127 : K_ENC;
  const int jl = tid >> 5, sub = tid & 31;
  const int j = wg * 16 + jl;                 // owned h index
  __shared__ float h_lds[32 * 20];            // [sub][16] padded to 20 (bank spread)

  float cst = 0.f;
  for (int t = 0; t < steps; ++t) {
    // weight slice + G0: issued BEFORE the poll; latency hides under it
    float4 w4[16];
    #pragma unroll
    for (int g = 0; g < 4; ++g)
      #pragma unroll
      for (int q = 0; q < 4; ++q)
        w4[g * 4 + q] = *(const float4*)&Whh[(g * HID + j) * HID + sub * 16 + q * 4];
    float g0i = G0[t * G4 + j];
    float g0f = G0[t * G4 + HID + j];
    float g0g = G0[t * G4 + 2 * HID + j];
    float g0o = G0[t * G4 + 3 * HID + j];
    // ---- poll tagged data: 4 waves, 2 words/lane, one dwordx4 sweep ----
    if (tid < 256) {
      const u64* src = hb + (t & 1) * 512 + tid * 2;
      i32x4 v;
      int guard = 0;
      for (;;) {
        asm volatile("global_load_dwordx4 %0, %1, off sc0 sc1\n\t"
                     "s_waitcnt vmcnt(0)"
                     : "=v"(v) : "v"(src) : "memory");
        if ((v[1] == t && v[3] == t) || ++guard >= STEP_GUARD) break;
        __builtin_amdgcn_s_sleep(1);
      }
      int k0 = tid * 2, k1 = k0 + 1;
      union { int u; float f; } c0, c1; c0.u = v[0]; c1.u = v[2];
      h_lds[(k0 >> 4) * 20 + (k0 & 15)] = c0.f;
      h_lds[(k1 >> 4) * 20 + (k1 & 15)] = c1.f;
    }
    __syncthreads();
    float h[16];
    #pragma unroll
    for (int kk = 0; kk < 16; ++kk) h[kk] = h_lds[sub * 20 + kk];
    float p0 = 0.f, p1 = 0.f, p2 = 0.f, p3 = 0.f;
    #pragma unroll
    for (int q = 0; q < 4; ++q) {
      p0 += w4[0+q].x*h[q*4+0] + w4[0+q].y*h[q*4+1] + w4[0+q].z*h[q*4+2] + w4[0+q].w*h[q*4+3];
      p1 += w4[4+q].x*h[q*4+0] + w4[4+q].y*h[q*4+1] + w4[4+q].z*h[q*4+2] + w4[4+q].w*h[q*4+3];
      p2 += w4[8+q].x*h[q*4+0] + w4[8+q].y*h[q*4+1] + w4[8+q].z*h[q*4+2] + w4[8+q].w*h[q*4+3];
      p3 += w4[12+q].x*h[q*4+0] + w4[12+q].y*h[q*4+1] + w4[12+q].z*h[q*4+2] + w4[12+q].w*h[q*4+3];
    }
    #pragma unroll
    for (int d = 1; d <= 16; d <<= 1) {       // reduce over 32 sub-lanes (stays in 32-half)
      p0 += __shfl_xor(p0, d); p1 += __shfl_xor(p1, d);
      p2 += __shfl_xor(p2, d); p3 += __shfl_xor(p3, d);
    }
    float si = fast_sigmoid(g0i + p0);
    float sf = fast_sigmoid(g0f + p1);
    float gG = fast_tanh(g0g + p2);
    float so = fast_sigmoid(g0o + p3);
    cst = sf * cst + si * gG;
    float hn = so * fast_tanh(cst);
    // publish h_{t+1}: one tagged atomicExch per owned index (MALL, async)
    if (sub == 0) {
      union { float f; unsigned u; } hu; hu.f = hn;
      u64 pack = ((u64)(unsigned)(t + 1) << 32) | (u64)hu.u;
      atomicExch(&hb[((t + 1) & 1) * 512 + j], pack);
      hs[t * HID + j] = hn;
    }
    __syncthreads();   // h_lds safe for next iteration's stagers
  }
}

// ---------------- EWe_s / DWd_s projections (scaled by log2e) ----------------
__global__ __launch_bounds__(256) void kProj(const float* __restrict__ Weh,
                                             const float* __restrict__ beh,
                                             float* __restrict__ ws) {
  int bid = blockIdx.x;                 // 0..190
  bool enc = bid < K_ENC;
  int row = enc ? bid : bid - K_ENC;
  const float* in = ws + (enc ? OFF_EENC : OFF_D) + row * HID;
  __shared__ float sin_[HID];
  int tid = threadIdx.x;
  sin_[tid] = in[tid]; sin_[tid + 256] = in[tid + 256];
  __syncthreads();
  if (tid < EMB) {
    const float* wr = Weh + tid * 1024 + (enc ? 0 : HID);
    float s = 0.f;
    #pragma unroll 4
    for (int h = 0; h < HID; ++h) s += sin_[h] * wr[h];
    if (!enc) s += beh[tid];
    ws[(enc ? OFF_EWE : OFF_DWD) + row * EMB + tid] = s * LOG2E;
  }
}

// ---------------- fused logits GEMM (bf16 MFMA) + online sum(2^s) ----------------
__global__ __launch_bounds__(256) void kLogits(float* __restrict__ ws) {
  const int t = blockIdx.x >> 2;
  const int chunk = blockIdx.x & 3;
  const int tid = threadIdx.x;
  const int lane = tid & 63;
  const int wv = tid >> 6;
  const int quad = lane >> 4, l15 = lane & 15;
  __shared__ __align__(16) unsigned short A[64 * 128];   // hpre_s bf16, [m][k] k-padded to 128
  const float* EWe = ws + OFF_EWE;
  const float* DWd = ws + OFF_DWD + t * EMB;
  for (int idx = tid; idx < 64 * 128; idx += 256) {
    int m = idx >> 7, k = idx & 127;
    float hv = 0.f;
    if (k < EMB) { float s = EWe[m * EMB + k] + DWd[k]; hv = s > 0.f ? s : 0.f; }
    A[idx] = f2bf(hv);
  }
  __syncthreads();
  short8 af[4][4];   // A fragments persistent in VGPRs: [mtile][kblock]
  #pragma unroll
  for (int mt = 0; mt < 4; ++mt)
    #pragma unroll
    for (int kb = 0; kb < 4; ++kb)
      af[mt][kb] = *(const short8*)&A[(mt * 16 + l15) * 128 + kb * 32 + quad * 8];
  const unsigned short* wem = (const unsigned short*)(ws + OFF_WEM);
  const float* bem_s = ws + OFF_BEM;
  float rs[4][4];
  #pragma unroll
  for (int a = 0; a < 4; ++a)
    #pragma unroll
    for (int b = 0; b < 4; ++b) rs[a][b] = 0.f;
  int vt = chunk * 500 + wv;
  short8 nb0, nb1, nb2, nb3; float nbi;
  nb0 = *(const short8*)&wem[(vt * 4 + 0) * 512 + lane * 8];
  nb1 = *(const short8*)&wem[(vt * 4 + 1) * 512 + lane * 8];
  nb2 = *(const short8*)&wem[(vt * 4 + 2) * 512 + lane * 8];
  nb3 = *(const short8*)&wem[(vt * 4 + 3) * 512 + lane * 8];
  nbi = bem_s[vt * 16 + l15];
  for (int ii = wv; ii < 500; ii += 4) {
    short8 cb0 = nb0, cb1 = nb1, cb2 = nb2, cb3 = nb3;
    float cbi = nbi;
    int nvt = vt + 4;
    if (ii + 4 < 500) {   // software pipeline next B tile
      nb0 = *(const short8*)&wem[(nvt * 4 + 0) * 512 + lane * 8];
      nb1 = *(const short8*)&wem[(nvt * 4 + 1) * 512 + lane * 8];
      nb2 = *(const short8*)&wem[(nvt * 4 + 2) * 512 + lane * 8];
      nb3 = *(const short8*)&wem[(nvt * 4 + 3) * 512 + lane * 8];
      nbi = bem_s[nvt * 16 + l15];
    }
    f32x4 acc[4];
    #pragma unroll
    for (int mt = 0; mt < 4; ++mt) acc[mt] = (f32x4){cbi, cbi, cbi, cbi};  // init with bem
    #pragma unroll
    for (int mt = 0; mt < 4; ++mt) {
      acc[mt] = __builtin_amdgcn_mfma_f32_16x16x32_bf16(af[mt][0], cb0, acc[mt], 0, 0, 0);
      acc[mt] = __builtin_amdgcn_mfma_f32_16x16x32_bf16(af[mt][1], cb1, acc[mt], 0, 0, 0);
      acc[mt] = __builtin_amdgcn_mfma_f32_16x16x32_bf16(af[mt][2], cb2, acc[mt], 0, 0, 0);
      acc[mt] = __builtin_amdgcn_mfma_f32_16x16x32_bf16(af[mt][3], cb3, acc[mt], 0, 0, 0);
    }
    #pragma unroll
    for (int mt = 0; mt < 4; ++mt)
      #pragma unroll
      for (int r = 0; r < 4; ++r)
        rs[mt][r] += __builtin_amdgcn_exp2f(acc[mt][r]);   // s already includes log2e scale
    vt = nvt;
  }
  // reduce across the 16 column-lanes of each quad, then one atomic per row
  #pragma unroll
  for (int d = 1; d < 16; d <<= 1)
    #pragma unroll
    for (int mt = 0; mt < 4; ++mt)
      #pragma unroll
      for (int r = 0; r < 4; ++r)
        rs[mt][r] += __shfl_xor(rs[mt][r], d);
  if (l15 == 0) {
    float* sum = ws + OFF_SUM + t * 64;
    #pragma unroll
    for (int mt = 0; mt < 4; ++mt)
      #pragma unroll
      for (int r = 0; r < 4; ++r)
        atomicAdd(&sum[mt * 16 + quad * 4 + r], rs[mt][r]);
  }
}

// ---------------- emission = ln2 * (s_word - log2(sum 2^s)), s_word in fp32 ----------------
__global__ __launch_bounds__(256) void kEmission(const int* __restrict__ y,
                                                 const float* __restrict__ Wem,
                                                 float* __restrict__ ws) {
  int gid = blockIdx.x * 256 + threadIdx.x;
  if (gid >= 127 * 64) return;
  int t = gid >> 6, m = gid & 63;
  const float* ew = ws + OFF_EWE + m * EMB;
  const float* dw = ws + OFF_DWD + t * EMB;
  int wt = y[t + 1];
  const float* wr = Wem + wt * EMB;
  float s = ws[OFF_BEM + wt];
  #pragma unroll 4
  for (int e = 0; e < EMB; ++e) {
    float h = ew[e] + dw[e];
    h = h > 0.f ? h : 0.f;
    s += h * wr[e];
  }
  ws[OFF_EM + gid] = LN2 * (s - __builtin_amdgcn_logf(ws[OFF_SUM + gid]));
}

// ---------------- Viterbi: prefix-max trick + backtrace ----------------
__global__ __launch_bounds__(256) void kViterbi(const float* __restrict__ ws, float* __restrict__ out) {
  __shared__ float em_lds[127 * 64];
  __shared__ int   inds[128 * 64];
  __shared__ float sval;
  const int tid = threadIdx.x;
  for (int i = tid; i < 127 * 64; i += 256) em_lds[i] = ws[OFF_EM + i];
  if (tid < 64) inds[tid] = 0;   // indices row 0
  __syncthreads();
  if (tid < 64) {
    const int j = tid;
    const float fs = -0.4054651081081644f;   // log(128/192)
    const float fe = -1.0986122886681098f;   // log(64/192)
    float pa = 0.f;
    float emnext = em_lds[j];
    for (int t = 0; t < 127; ++t) {
      float emc = emnext;
      if (t < 126) emnext = em_lds[(t + 1) * 64 + j];
      float v = fmaf(-fs, (float)j, pa);   // q[j]
      int idx = j;
      #pragma unroll
      for (int d = 1; d < 64; d <<= 1) {   // inclusive prefix max, earliest argmax on ties
        float vv = __shfl_up(v, d);
        int   ii = __shfl_up(idx, d);
        bool cur = v > vv;                 // strict >: keep earlier index on ties
        v   = cur ? v : vv;
        idx = cur ? idx : ii;
      }
      pa = v + fe + fs * (float)j + emc;
      inds[(t + 1) * 64 + j] = idx;
    }
    if (j == 63) sval = pa;
  }
  __syncthreads();
  if (tid == 0) {
    int ind = 63;
    for (int t = 127; t >= 0; --t) {
      ind = inds[t * 64 + ind];
      out[t] = (float)ind;
    }
    out[128] = sval;
  }
}

extern "C" void kernel_launch(void* const* d_in, const int* in_sizes, int n_in,
                              void* d_out, int out_size, void* d_ws, size_t ws_size,
                              hipStream_t stream) {
  const int*   x    = (const int*)d_in[0];
  const int*   y    = (const int*)d_in[1];
  const float* emb  = (const float*)d_in[2];
  const float* eWih = (const float*)d_in[3];
  const float* eWhh = (const float*)d_in[4];
  const float* ebih = (const float*)d_in[5];
  const float* ebhh = (const float*)d_in[6];
  const float* dWih = (const float*)d_in[7];
  const float* dWhh = (const float*)d_in[8];
  const float* dbih = (const float*)d_in[9];
  const float* dbhh = (const float*)d_in[10];
  const float* Weh  = (const float*)d_in[11];
  const float* beh  = (const float*)d_in[12];
  const float* Wem  = (const float*)d_in[13];
  const float* bem  = (const float*)d_in[14];
  float* ws  = (float*)d_ws;
  float* out = (float*)d_out;

  hipLaunchKernelGGL(kPrep0,    dim3(PREP_G0_BLKS + 49), dim3(256), 0, stream,
                     x, y, emb, eWih, ebih, ebhh, dWih, dbih, dbhh, ws);
  hipLaunchKernelGGL(kLstm,     dim3(64 + 8000), dim3(512), 0, stream, eWhh, dWhh, Wem, bem, ws);
  hipLaunchKernelGGL(kProj,     dim3(191),   dim3(256), 0, stream, Weh, beh, ws);
  hipLaunchKernelGGL(kLogits,   dim3(508),   dim3(256), 0, stream, ws);
  hipLaunchKernelGGL(kEmission, dim3(32),    dim3(256), 0, stream, y, Wem, ws);
  hipLaunchKernelGGL(kViterbi,  dim3(1),     dim3(256), 0, stream, ws, out);
}

// Round 16
// 507.762 us; speedup vs baseline: 1.3315x; 1.0103x over previous
//
#include <hip/hip_runtime.h>

// Seq2SeqWithAlignment: enc/dec LSTM -> hpre -> logits logsumexp -> Viterbi align.
// K=64 enc steps, T=128 dec tokens (127 dec steps used), H=512, E=100, V=32000.

#define K_ENC 64
#define HID   512
#define EMB   100
#define VOC   32000
#define G4    2048   // 4*HID

typedef __attribute__((ext_vector_type(8))) short  short8;
typedef __attribute__((ext_vector_type(4))) float  f32x4;
typedef __attribute__((ext_vector_type(4))) int    i32x4;
typedef unsigned long long u64;

#define LOG2E 1.4426950408889634f
#define LN2   0.6931471805599453f

__device__ __forceinline__ unsigned short f2bf(float f) {
  union { float f; unsigned u; } x; x.f = f;
  unsigned r = x.u + 0x7FFFu + ((x.u >> 16) & 1u);  // RNE
  return (unsigned short)(r >> 16);
}

__device__ __forceinline__ float fast_sigmoid(float x) {
  return __builtin_amdgcn_rcpf(1.f + __builtin_amdgcn_exp2f(-LOG2E * x));
}
__device__ __forceinline__ float fast_tanh(float x) {
  return 1.f - 2.f * __builtin_amdgcn_rcpf(1.f + __builtin_amdgcn_exp2f(2.f * LOG2E * x));
}

// ---------------- workspace layout (float offsets) ----------------
#define OFF_PAD   0         // 256 floats: scratch (zeroed)
#define OFF_HBUF  256       // 4096 floats = 2048 u64: tagged h channels [grp][slot][512]
#define OFF_G0E   4352      // 64*2048  : enc Wih@x + bih + bhh
#define OFF_G0D   135424    // 127*2048 : dec
#define OFF_EENC  395520    // 64*512
#define OFF_D     428288    // 127*512
#define OFF_EWE   493312    // 64*100   : log2e * Eenc@We_E^T
#define OFF_DWD   499712    // 127*100  : log2e * (D@We_D^T + beh)
#define OFF_BEM   512412    // 32000    : log2e * bem
#define OFF_SUM   544412    // 127*64   : sum of 2^s over v (atomic)
#define OFF_EM    552540    // 127*64   : emission
#define OFF_WEM   560668    // ushort[4096000]: Wem bf16 in MFMA-B fragment-linear layout
// total ~10.4 MB

// ---------------- serial prep: G0 (1528 blks) + zero-init (49 blks) ----------------
#define PREP_G0_BLKS 1528
__global__ __launch_bounds__(256) void kPrep0(const int* __restrict__ x, const int* __restrict__ y,
                    const float* __restrict__ emb,
                    const float* __restrict__ eWih, const float* __restrict__ ebih,
                    const float* __restrict__ ebhh,
                    const float* __restrict__ dWih, const float* __restrict__ dbih,
                    const float* __restrict__ dbhh,
                    float* __restrict__ ws) {
  const int b = blockIdx.x;
  const int tid = threadIdx.x;
  if (b < PREP_G0_BLKS) {
    // G0 = Wih @ emb[tok] + bih + bhh
    int gid = b * 256 + tid;
    const int enc_total = K_ENC * G4;
    if (gid >= enc_total + 127 * G4) return;
    bool enc = gid < enc_total;
    int loc = enc ? gid : gid - enc_total;
    int t = loc >> 11, r = loc & (G4 - 1);
    int tok = enc ? x[t] : y[t];
    const float* Wr = (enc ? eWih : dWih) + r * EMB;
    const float* er = emb + tok * EMB;
    float s = 0.f;
    #pragma unroll 4
    for (int e = 0; e < EMB; ++e) s += er[e] * Wr[e];
    s += enc ? (ebih[r] + ebhh[r]) : (dbih[r] + dbhh[r]);
    ws[(enc ? OFF_G0E : OFF_G0D) + t * G4 + r] = s;
  } else {
    // zero init: scratch + tagged h channels (tag0/val0) + sumexp
    int gid = (b - PREP_G0_BLKS) * 256 + tid;
    if (gid < 4352) ws[gid] = 0.f;
    else if (gid < 4352 + 127 * 64) ws[OFF_SUM + gid - 4352] = 0.f;
  }
}

// ---------------- persistent LSTM (64 sync WGs) + overlapped Wem-prep (8000 WGs) ----------------
// Transport ledger (R0..R13): only MALL-coherent ops are promptly visible
// cross-CU. Proven fastest (R10/R13, 1.86-1.97us/step): atomicExch tagged
// publish + throttled sc0 sc1 dwordx4 poll + end-of-step barrier. R13 verified:
// 8000 prep WGs overlap in the sync loop's shadow (kLstm 250us, prediction hit).
// Poll is BOUNDED: guard expiry => finite wrong answer, never a hang.
#define STEP_GUARD 16384

__global__ __launch_bounds__(512, 2) void kLstm(const float* __restrict__ eWhh,
                                                const float* __restrict__ dWhh,
                                                const float* __restrict__ Wem,
                                                const float* __restrict__ bem,
                                                float* __restrict__ ws) {
  const int b = blockIdx.x;
  const int tid = threadIdx.x;
  if (b >= 64) {
    // ---- Wem -> bf16 MFMA-B fragment-linear layout; bem scaled (overlapped) ----
    int gid = (b - 64) * 512 + tid;             // < 4,096,000 = 8000*512
    int vt = gid >> 11;
    int kb = (gid >> 9) & 3;
    int L  = (gid >> 3) & 63;
    int j  = gid & 7;
    int v = vt * 16 + (L & 15);
    int k = kb * 32 + ((L >> 4) << 3) + j;
    float val = (k < EMB) ? Wem[v * EMB + k] : 0.f;
    ((unsigned short*)(ws + OFF_WEM))[gid] = f2bf(val);
    if (gid < VOC) ws[OFF_BEM + gid] = bem[gid] * LOG2E;
    return;
  }
  const int grp = b >> 5;                     // 0=enc, 1=dec
  const int wg  = b & 31;
  const float* __restrict__ Whh = grp ? dWhh : eWhh;
  const float* __restrict__ G0  = ws + (grp ? OFF_G0D : OFF_G0E);
  float* hs = ws + (grp ? OFF_D : OFF_EENC);
  u64* hb = (u64*)(ws + OFF_HBUF) + grp * 1024;   // [2][512] tagged words
  const int steps = grp ? 127 : K_ENC;
  const int jl = tid >> 5, sub = tid & 31;
  const int j = wg * 16 + jl;                 // owned h index
  __shared__ float h_lds[32 * 20];            // [sub][16] padded to 20 (bank spread)

  float cst = 0.f;
  for (int t = 0; t < steps; ++t) {
    // weight slice + G0: issued BEFORE the poll; latency hides under it
    float4 w4[16];
    #pragma unroll
    for (int g = 0; g < 4; ++g)
      #pragma unroll
      for (int q = 0; q < 4; ++q)
        w4[g * 4 + q] = *(const float4*)&Whh[(g * HID + j) * HID + sub * 16 + q * 4];
    float g0i = G0[t * G4 + j];
    float g0f = G0[t * G4 + HID + j];
    float g0g = G0[t * G4 + 2 * HID + j];
    float g0o = G0[t * G4 + 3 * HID + j];
    // ---- poll tagged data: 4 waves, 2 words/lane, one dwordx4 sweep ----
    if (tid < 256) {
      const u64* src = hb + (t & 1) * 512 + tid * 2;
      i32x4 v;
      int guard = 0;
      for (;;) {
        asm volatile("global_load_dwordx4 %0, %1, off sc0 sc1\n\t"
                     "s_waitcnt vmcnt(0)"
                     : "=v"(v) : "v"(src) : "memory");
        if ((v[1] == t && v[3] == t) || ++guard >= STEP_GUARD) break;
        __builtin_amdgcn_s_sleep(1);
      }
      int k0 = tid * 2, k1 = k0 + 1;
      union { int u; float f; } c0, c1; c0.u = v[0]; c1.u = v[2];
      h_lds[(k0 >> 4) * 20 + (k0 & 15)] = c0.f;
      h_lds[(k1 >> 4) * 20 + (k1 & 15)] = c1.f;
    }
    __syncthreads();
    float h[16];
    #pragma unroll
    for (int kk = 0; kk < 16; ++kk) h[kk] = h_lds[sub * 20 + kk];
    float p0 = 0.f, p1 = 0.f, p2 = 0.f, p3 = 0.f;
    #pragma unroll
    for (int q = 0; q < 4; ++q) {
      p0 += w4[0+q].x*h[q*4+0] + w4[0+q].y*h[q*4+1] + w4[0+q].z*h[q*4+2] + w4[0+q].w*h[q*4+3];
      p1 += w4[4+q].x*h[q*4+0] + w4[4+q].y*h[q*4+1] + w4[4+q].z*h[q*4+2] + w4[4+q].w*h[q*4+3];
      p2 += w4[8+q].x*h[q*4+0] + w4[8+q].y*h[q*4+1] + w4[8+q].z*h[q*4+2] + w4[8+q].w*h[q*4+3];
      p3 += w4[12+q].x*h[q*4+0] + w4[12+q].y*h[q*4+1] + w4[12+q].z*h[q*4+2] + w4[12+q].w*h[q*4+3];
    }
    #pragma unroll
    for (int d = 1; d <= 16; d <<= 1) {       // reduce over 32 sub-lanes (stays in 32-half)
      p0 += __shfl_xor(p0, d); p1 += __shfl_xor(p1, d);
      p2 += __shfl_xor(p2, d); p3 += __shfl_xor(p3, d);
    }
    float si = fast_sigmoid(g0i + p0);
    float sf = fast_sigmoid(g0f + p1);
    float gG = fast_tanh(g0g + p2);
    float so = fast_sigmoid(g0o + p3);
    cst = sf * cst + si * gG;
    float hn = so * fast_tanh(cst);
    // publish h_{t+1}: one tagged atomicExch per owned index (MALL, async)
    if (sub == 0) {
      union { float f; unsigned u; } hu; hu.f = hn;
      u64 pack = ((u64)(unsigned)(t + 1) << 32) | (u64)hu.u;
      atomicExch(&hb[((t + 1) & 1) * 512 + j], pack);
      hs[t * HID + j] = hn;
    }
    __syncthreads();   // h_lds safe for next iteration's stagers
  }
}

// ---------------- EWe_s / DWd_s projections (scaled by log2e) ----------------
__global__ __launch_bounds__(256) void kProj(const float* __restrict__ Weh,
                                             const float* __restrict__ beh,
                                             float* __restrict__ ws) {
  int bid = blockIdx.x;                 // 0..190
  bool enc = bid < K_ENC;
  int row = enc ? bid : bid - K_ENC;
  const float* in = ws + (enc ? OFF_EENC : OFF_D) + row * HID;
  __shared__ float sin_[HID];
  int tid = threadIdx.x;
  sin_[tid] = in[tid]; sin_[tid + 256] = in[tid + 256];
  __syncthreads();
  if (tid < EMB) {
    const float* wr = Weh + tid * 1024 + (enc ? 0 : HID);
    float s = 0.f;
    #pragma unroll 4
    for (int h = 0; h < HID; ++h) s += sin_[h] * wr[h];
    if (!enc) s += beh[tid];
    ws[(enc ? OFF_EWE : OFF_DWD) + row * EMB + tid] = s * LOG2E;
  }
}

// ---------------- fused logits GEMM (bf16 MFMA) + online sum(2^s), 2 t's/block ----------------
// R15: Wem (8MB bf16) was re-read once per t (127x ~= 1GB L3 traffic). Each
// block now serves TWO t's with BOTH A-fragment sets VGPR-resident
// (af[2][4][4] = 128 VGPR; no inner-loop LDS reads, unlike R11's failed 4-t
// LDS variant) -> each B-tile load feeds 32 MFMAs instead of 16, Wem traffic
// halves (~500MB). Grid 64 t-pairs x 8 chunks; t=127 guard on final pair.
__global__ __launch_bounds__(256) void kLogits(float* __restrict__ ws) {
  const int tg = blockIdx.x >> 3;        // 0..63 (t = 2*tg, 2*tg+1)
  const int chunk = blockIdx.x & 7;      // 0..7  (250 v-tiles each)
  const int tid = threadIdx.x;
  const int lane = tid & 63;
  const int wv = tid >> 6;
  const int quad = lane >> 4, l15 = lane & 15;
  __shared__ __align__(16) unsigned short A[2][64 * 128];  // hpre_s bf16, k-padded
  const float* EWe = ws + OFF_EWE;
  const int t0 = tg * 2;
  const int t1v = (t0 + 1 <= 126) ? (t0 + 1) : 126;        // clamped (guarded at add)
  const float* DWd0 = ws + OFF_DWD + t0 * EMB;
  const float* DWd1 = ws + OFF_DWD + t1v * EMB;
  for (int idx = tid; idx < 64 * 128; idx += 256) {
    int m = idx >> 7, k = idx & 127;
    float hv0 = 0.f, hv1 = 0.f;
    if (k < EMB) {
      float e = EWe[m * EMB + k];
      float s0 = e + DWd0[k]; hv0 = s0 > 0.f ? s0 : 0.f;
      float s1 = e + DWd1[k]; hv1 = s1 > 0.f ? s1 : 0.f;
    }
    A[0][idx] = f2bf(hv0);
    A[1][idx] = f2bf(hv1);
  }
  __syncthreads();
  short8 af[2][4][4];   // BOTH t's A fragments persistent in VGPRs
  #pragma unroll
  for (int ts = 0; ts < 2; ++ts)
    #pragma unroll
    for (int mt = 0; mt < 4; ++mt)
      #pragma unroll
      for (int kb = 0; kb < 4; ++kb)
        af[ts][mt][kb] = *(const short8*)&A[ts][(mt * 16 + l15) * 128 + kb * 32 + quad * 8];
  const unsigned short* wem = (const unsigned short*)(ws + OFF_WEM);
  const float* bem_s = ws + OFF_BEM;
  float rs[2][4][4];
  #pragma unroll
  for (int ts = 0; ts < 2; ++ts)
    #pragma unroll
    for (int a = 0; a < 4; ++a)
      #pragma unroll
      for (int c = 0; c < 4; ++c) rs[ts][a][c] = 0.f;
  int vt = chunk * 250 + wv;
  short8 nb0, nb1, nb2, nb3; float nbi;
  nb0 = *(const short8*)&wem[(vt * 4 + 0) * 512 + lane * 8];
  nb1 = *(const short8*)&wem[(vt * 4 + 1) * 512 + lane * 8];
  nb2 = *(const short8*)&wem[(vt * 4 + 2) * 512 + lane * 8];
  nb3 = *(const short8*)&wem[(vt * 4 + 3) * 512 + lane * 8];
  nbi = bem_s[vt * 16 + l15];
  for (int ii = wv; ii < 250; ii += 4) {
    short8 cb0 = nb0, cb1 = nb1, cb2 = nb2, cb3 = nb3;
    float cbi = nbi;
    int nvt = vt + 4;
    if (ii + 4 < 250) {   // software pipeline next B tile
      nb0 = *(const short8*)&wem[(nvt * 4 + 0) * 512 + lane * 8];
      nb1 = *(const short8*)&wem[(nvt * 4 + 1) * 512 + lane * 8];
      nb2 = *(const short8*)&wem[(nvt * 4 + 2) * 512 + lane * 8];
      nb3 = *(const short8*)&wem[(nvt * 4 + 3) * 512 + lane * 8];
      nbi = bem_s[nvt * 16 + l15];
    }
    #pragma unroll
    for (int ts = 0; ts < 2; ++ts) {
      f32x4 acc[4];
      #pragma unroll
      for (int mt = 0; mt < 4; ++mt) acc[mt] = (f32x4){cbi, cbi, cbi, cbi};  // init with bem
      #pragma unroll
      for (int mt = 0; mt < 4; ++mt) {
        acc[mt] = __builtin_amdgcn_mfma_f32_16x16x32_bf16(af[ts][mt][0], cb0, acc[mt], 0, 0, 0);
        acc[mt] = __builtin_amdgcn_mfma_f32_16x16x32_bf16(af[ts][mt][1], cb1, acc[mt], 0, 0, 0);
        acc[mt] = __builtin_amdgcn_mfma_f32_16x16x32_bf16(af[ts][mt][2], cb2, acc[mt], 0, 0, 0);
        acc[mt] = __builtin_amdgcn_mfma_f32_16x16x32_bf16(af[ts][mt][3], cb3, acc[mt], 0, 0, 0);
      }
      #pragma unroll
      for (int mt = 0; mt < 4; ++mt)
        #pragma unroll
        for (int r = 0; r < 4; ++r)
          rs[ts][mt][r] += __builtin_amdgcn_exp2f(acc[mt][r]);   // log2e-scaled s
    }
    vt = nvt;
  }
  // reduce across the 16 column-lanes of each quad, then one atomic per row
  #pragma unroll
  for (int d = 1; d < 16; d <<= 1)
    #pragma unroll
    for (int ts = 0; ts < 2; ++ts)
      #pragma unroll
      for (int mt = 0; mt < 4; ++mt)
        #pragma unroll
        for (int r = 0; r < 4; ++r)
          rs[ts][mt][r] += __shfl_xor(rs[ts][mt][r], d);
  if (l15 == 0) {
    #pragma unroll
    for (int ts = 0; ts < 2; ++ts) {
      int t = t0 + ts;
      if (t <= 126) {
        float* sum = ws + OFF_SUM + t * 64;
        #pragma unroll
        for (int mt = 0; mt < 4; ++mt)
          #pragma unroll
          for (int r = 0; r < 4; ++r)
            atomicAdd(&sum[mt * 16 + quad * 4 + r], rs[ts][mt][r]);
      }
    }
  }
}

// ---------------- emission = ln2 * (s_word - log2(sum 2^s)), s_word in fp32 ----------------
__global__ __launch_bounds__(256) void kEmission(const int* __restrict__ y,
                                                 const float* __restrict__ Wem,
                                                 float* __restrict__ ws) {
  int gid = blockIdx.x * 256 + threadIdx.x;
  if (gid >= 127 * 64) return;
  int t = gid >> 6, m = gid & 63;
  const float* ew = ws + OFF_EWE + m * EMB;
  const float* dw = ws + OFF_DWD + t * EMB;
  int wt = y[t + 1];
  const float* wr = Wem + wt * EMB;
  float s = ws[OFF_BEM + wt];
  #pragma unroll 4
  for (int e = 0; e < EMB; ++e) {
    float h = ew[e] + dw[e];
    h = h > 0.f ? h : 0.f;
    s += h * wr[e];
  }
  ws[OFF_EM + gid] = LN2 * (s - __builtin_amdgcn_logf(ws[OFF_SUM + gid]));
}

// ---------------- Viterbi: prefix-max trick + backtrace ----------------
__global__ __launch_bounds__(256) void kViterbi(const float* __restrict__ ws, float* __restrict__ out) {
  __shared__ float em_lds[127 * 64];
  __shared__ int   inds[128 * 64];
  __shared__ float sval;
  const int tid = threadIdx.x;
  for (int i = tid; i < 127 * 64; i += 256) em_lds[i] = ws[OFF_EM + i];
  if (tid < 64) inds[tid] = 0;   // indices row 0
  __syncthreads();
  if (tid < 64) {
    const int j = tid;
    const float fs = -0.4054651081081644f;   // log(128/192)
    const float fe = -1.0986122886681098f;   // log(64/192)
    float pa = 0.f;
    float emnext = em_lds[j];
    for (int t = 0; t < 127; ++t) {
      float emc = emnext;
      if (t < 126) emnext = em_lds[(t + 1) * 64 + j];
      float v = fmaf(-fs, (float)j, pa);   // q[j]
      int idx = j;
      #pragma unroll
      for (int d = 1; d < 64; d <<= 1) {   // inclusive prefix max, earliest argmax on ties
        float vv = __shfl_up(v, d);
        int   ii = __shfl_up(idx, d);
        bool cur = v > vv;                 // strict >: keep earlier index on ties
        v   = cur ? v : vv;
        idx = cur ? idx : ii;
      }
      pa = v + fe + fs * (float)j + emc;
      inds[(t + 1) * 64 + j] = idx;
    }
    if (j == 63) sval = pa;
  }
  __syncthreads();
  if (tid == 0) {
    int ind = 63;
    for (int t = 127; t >= 0; --t) {
      ind = inds[t * 64 + ind];
      out[t] = (float)ind;
    }
    out[128] = sval;
  }
}

extern "C" void kernel_launch(void* const* d_in, const int* in_sizes, int n_in,
                              void* d_out, int out_size, void* d_ws, size_t ws_size,
                              hipStream_t stream) {
  const int*   x    = (const int*)d_in[0];
  const int*   y    = (const int*)d_in[1];
  const float* emb  = (const float*)d_in[2];
  const float* eWih = (const float*)d_in[3];
  const float* eWhh = (const float*)d_in[4];
  const float* ebih = (const float*)d_in[5];
  const float* ebhh = (const float*)d_in[6];
  const float* dWih = (const float*)d_in[7];
  const float* dWhh = (const float*)d_in[8];
  const float* dbih = (const float*)d_in[9];
  const float* dbhh = (const float*)d_in[10];
  const float* Weh  = (const float*)d_in[11];
  const float* beh  = (const float*)d_in[12];
  const float* Wem  = (const float*)d_in[13];
  const float* bem  = (const float*)d_in[14];
  float* ws  = (float*)d_ws;
  float* out = (float*)d_out;

  hipLaunchKernelGGL(kPrep0,    dim3(PREP_G0_BLKS + 49), dim3(256), 0, stream,
                     x, y, emb, eWih, ebih, ebhh, dWih, dbih, dbhh, ws);
  hipLaunchKernelGGL(kLstm,     dim3(64 + 8000), dim3(512), 0, stream, eWhh, dWhh, Wem, bem, ws);
  hipLaunchKernelGGL(kProj,     dim3(191),   dim3(256), 0, stream, Weh, beh, ws);
  hipLaunchKernelGGL(kLogits,   dim3(512),   dim3(256), 0, stream, ws);
  hipLaunchKernelGGL(kEmission, dim3(32),    dim3(256), 0, stream, y, Wem, ws);
  hipLaunchKernelGGL(kViterbi,  dim3(1),     dim3(256), 0, stream, ws, out);
}